// Round 3
// baseline (1649.897 us; speedup 1.0000x reference)
//
#include <hip/hip_runtime.h>
#include <hip/hip_bf16.h>

#define NN 50000
#define NE 1200000
#define DIN 128
#define HDIM 64
#define NG 64
#define EPSV 1e-5f

__device__ __forceinline__ float b2f(const __hip_bfloat16 v) { return __bfloat162float(v); }

// dual-dtype load: isbf16 selects interpretation of the raw input pointer
__device__ __forceinline__ float ldf(const void* p, size_t idx, int isbf16) {
    return isbf16 ? b2f(((const __hip_bfloat16*)p)[idx]) : ((const float*)p)[idx];
}

// ---------------- dtype detection ----------------
// Scan x reinterpreted as uint16 halves. A genuine-bf16 buffer of neural data
// never contains exponent 0xFF (inf/nan). An fp32 buffer's low halves are
// ~uniform random bits -> ~0.4% of halves match. count>=4 <=> fp32.
__global__ void k_detect(const unsigned short* __restrict__ x, int* __restrict__ cnt, int n) {
    int i = blockIdx.x * 256 + threadIdx.x;
    if (i < n) {
        unsigned short u = x[i];
        if (((u >> 7) & 0xFF) == 0xFF) atomicAdd(cnt, 1);  // per-wave coalesced
    }
}

// flag = 1 if bf16, 0 if fp32
__global__ void k_resolve(const int* __restrict__ cnt, int* __restrict__ flag) {
    if (threadIdx.x == 0 && blockIdx.x == 0) *flag = (*cnt < 4) ? 1 : 0;
}

// ---------------- param conversion into fp32 workspace ----------------
#define PW_WIN   0
#define PW_BIN   8192
#define PW_GCNW  8256
#define PW_GCNB  16448
#define PW_GCNBN 16576
#define PW_SWL   17088
#define PW_SWR   25280
#define PW_SB    33472
#define PW_SBN   33600
#define PW_F1W   34112
#define PW_F1B   42304
#define PW_BN1   42368
#define PW_F2W   42624
#define PW_F2B   44672
#define PW_BN2   44704
#define PW_F3W   44832
#define PW_F3B   44864
#define PW_TOT   44865

struct PSrc { const void* p[17]; };

__global__ void k_cvt(PSrc s, const int* __restrict__ flag, float* __restrict__ dst) {
    const int offs[18] = {PW_WIN, PW_BIN, PW_GCNW, PW_GCNB, PW_GCNBN, PW_SWL, PW_SWR,
                          PW_SB, PW_SBN, PW_F1W, PW_F1B, PW_BN1, PW_F2W, PW_F2B,
                          PW_BN2, PW_F3W, PW_F3B, PW_TOT};
    int i = blockIdx.x * 256 + threadIdx.x;
    if (i >= PW_TOT) return;
    int f = *flag;
    int seg = 0;
    while (i >= offs[seg + 1]) ++seg;
    dst[i] = ldf(s.p[seg], i - offs[seg], f);
}

// ---------------- degree / prep ----------------
__global__ void k_degree(const int* __restrict__ dst, int* __restrict__ indeg, int E) {
    int e = blockIdx.x * 256 + threadIdx.x;
    if (e < E) atomicAdd(&indeg[dst[e]], 1);
}

__global__ void k_gcount(const int* __restrict__ batch, int* __restrict__ gcnt, int n) {
    int v = blockIdx.x * 256 + threadIdx.x;
    if (v < n) atomicAdd(&gcnt[batch[v]], 1);
}

__global__ void k_prep(const int* __restrict__ indeg, float* __restrict__ dinv,
                       float* __restrict__ cinv, int n) {
    int v = blockIdx.x * 256 + threadIdx.x;
    if (v < n) {
        float d = (float)indeg[v];
        dinv[v] = rsqrtf(d + 1.0f);          // GCN deg includes self-loop, always > 0
        cinv[v] = 1.0f / fmaxf(d, 1.0f);     // SAGE mean denominator
    }
}

// ---------------- tiled GEMM helpers (64-node x 64-feat tile, 256 threads) ----------------
__device__ __forceinline__ void mac16(float acc[4][4], const float4 av, const float4 wv) {
    float a[4] = {av.x, av.y, av.z, av.w};
    float w[4] = {wv.x, wv.y, wv.z, wv.w};
#pragma unroll
    for (int i = 0; i < 4; i++)
#pragma unroll
        for (int j = 0; j < 4; j++) acc[i][j] = fmaf(a[i], w[j], acc[i][j]);
}

// h = relu(x @ W_in + b_in); x is raw input (dtype per flag), W/b fp32 from params
__global__ __launch_bounds__(256) void k_in_gemm(const void* __restrict__ A,
                                                 const float* __restrict__ W,
                                                 const float* __restrict__ bias,
                                                 const int* __restrict__ flag,
                                                 float* __restrict__ out, int n) {
    __shared__ float As[64][68];
    __shared__ float Ws[64][64];
    int t = threadIdx.x;
    int v0 = blockIdx.x * 64;
    int tx = t & 15, ty = t >> 4;
    int f16 = *flag;
    float acc[4][4] = {};
    for (int k0 = 0; k0 < 128; k0 += 64) {
#pragma unroll
        for (int j = 0; j < 16; ++j) {
            int i = t + 256 * j;
            int r = i >> 6, k = i & 63;
            int v = v0 + r;
            As[k][r] = (v < n) ? ldf(A, (size_t)v * DIN + k0 + k, f16) : 0.0f;
        }
#pragma unroll
        for (int j = 0; j < 16; ++j) {
            int i = t + 256 * j;
            int kk = i >> 6, f = i & 63;
            Ws[kk][f] = W[(k0 + kk) * 64 + f];
        }
        __syncthreads();
#pragma unroll 8
        for (int k = 0; k < 64; ++k) {
            float4 wv = *(const float4*)&Ws[k][tx * 4];
            float4 av = *(const float4*)&As[k][ty * 4];
            mac16(acc, av, wv);
        }
        __syncthreads();
    }
#pragma unroll
    for (int i = 0; i < 4; i++) {
        int v = v0 + ty * 4 + i;
        if (v < n) {
#pragma unroll
            for (int j = 0; j < 4; j++) {
                int f = tx * 4 + j;
                float y = acc[i][j] + bias[f];
                out[(size_t)v * 64 + f] = fmaxf(y, 0.0f);
            }
        }
    }
}

// T = A @ W ; outInit = T * dinv[v]  (self-loop term doubles as zero-init of agg buffer)
// Safe when T aliases A: each block reads only its own 64-row tile (into LDS,
// fully consumed before the writes to the same rows).
__global__ __launch_bounds__(256) void k_gcn_gemm(const float* __restrict__ A,
                                                  const float* __restrict__ W,
                                                  const float* __restrict__ dinv,
                                                  float* __restrict__ T,
                                                  float* __restrict__ outInit, int n) {
    __shared__ float As[64][68];
    __shared__ float Ws[64][64];
    int t = threadIdx.x;
    int v0 = blockIdx.x * 64;
    int tx = t & 15, ty = t >> 4;
    float acc[4][4] = {};
#pragma unroll
    for (int j = 0; j < 16; ++j) {
        int i = t + 256 * j;
        int r = i >> 6, k = i & 63;
        int v = v0 + r;
        As[k][r] = (v < n) ? A[(size_t)v * 64 + k] : 0.0f;
    }
#pragma unroll
    for (int j = 0; j < 16; ++j) {
        int i = t + 256 * j;
        int kk = i >> 6, f = i & 63;
        Ws[kk][f] = W[kk * 64 + f];
    }
    __syncthreads();
#pragma unroll 8
    for (int k = 0; k < 64; ++k) {
        float4 wv = *(const float4*)&Ws[k][tx * 4];
        float4 av = *(const float4*)&As[k][ty * 4];
        mac16(acc, av, wv);
    }
#pragma unroll
    for (int i = 0; i < 4; i++) {
        int v = v0 + ty * 4 + i;
        if (v < n) {
            float dv = dinv[v];
#pragma unroll
            for (int j = 0; j < 4; j++) {
                int f = tx * 4 + j;
                size_t o = (size_t)v * 64 + f;
                T[o] = acc[i][j];
                outInit[o] = acc[i][j] * dv;
            }
        }
    }
}

// out = relu(bn( (agg*cinv[v]) @ Wl + X @ Wr + b ))
__global__ __launch_bounds__(256) void k_sage_gemm(const float* __restrict__ AGG,
                                                   const float* __restrict__ X,
                                                   const float* __restrict__ Wl,
                                                   const float* __restrict__ Wr,
                                                   const float* __restrict__ bias,
                                                   const float* __restrict__ bn,
                                                   const float* __restrict__ cinv,
                                                   float* __restrict__ out, int n) {
    __shared__ float As[64][68];
    __shared__ float Ws[64][64];
    int t = threadIdx.x;
    int v0 = blockIdx.x * 64;
    int tx = t & 15, ty = t >> 4;
    float acc[4][4] = {};
    for (int pass = 0; pass < 2; ++pass) {
        const float* Ap = pass ? X : AGG;
        const float* Wp = pass ? Wr : Wl;
#pragma unroll
        for (int j = 0; j < 16; ++j) {
            int i = t + 256 * j;
            int r = i >> 6, k = i & 63;
            int v = v0 + r;
            float val = 0.0f;
            if (v < n) {
                val = Ap[(size_t)v * 64 + k];
                if (pass == 0) val *= cinv[v];
            }
            As[k][r] = val;
        }
#pragma unroll
        for (int j = 0; j < 16; ++j) {
            int i = t + 256 * j;
            int kk = i >> 6, f = i & 63;
            Ws[kk][f] = Wp[kk * 64 + f];
        }
        __syncthreads();
#pragma unroll 8
        for (int k = 0; k < 64; ++k) {
            float4 wv = *(const float4*)&Ws[k][tx * 4];
            float4 av = *(const float4*)&As[k][ty * 4];
            mac16(acc, av, wv);
        }
        __syncthreads();
    }
#pragma unroll
    for (int i = 0; i < 4; i++) {
        int v = v0 + ty * 4 + i;
        if (v < n) {
#pragma unroll
            for (int j = 0; j < 4; j++) {
                int f = tx * 4 + j;
                float y = acc[i][j] + bias[f];
                y = (y - bn[128 + f]) * rsqrtf(bn[192 + f] + EPSV) * bn[f] + bn[64 + f];
                out[(size_t)v * 64 + f] = fmaxf(y, 0.0f);
            }
        }
    }
}

// GCN epilogue: out = relu(bn(dinv[v]*agg + b))
__global__ void k_gcn_post(const float* __restrict__ agg, const float* __restrict__ dinv,
                           const float* __restrict__ bias,
                           const float* __restrict__ bn,
                           float* __restrict__ out, int n) {
    int idx = blockIdx.x * 256 + threadIdx.x;
    if (idx >= n * 64) return;
    int v = idx >> 6, f = idx & 63;
    float y = dinv[v] * agg[idx] + bias[f];
    y = (y - bn[128 + f]) * rsqrtf(bn[192 + f] + EPSV) * bn[f] + bn[64 + f];
    out[idx] = fmaxf(y, 0.0f);
}

// ---------------- edge scatter (atomics), 64 feats = 1 wave-row per edge ----------------
__global__ __launch_bounds__(256) void k_gcn_scatter(const float* __restrict__ T,
                                                     const float* __restrict__ dinv,
                                                     const int* __restrict__ src,
                                                     const int* __restrict__ dst,
                                                     float* __restrict__ out, int E) {
    int e = blockIdx.x * 4 + threadIdx.y;
    if (e >= E) return;
    int s = src[e], d = dst[e];
    float w = dinv[s];
    int f = threadIdx.x;
    atomicAdd(&out[(size_t)d * 64 + f], T[(size_t)s * 64 + f] * w);
}

__global__ __launch_bounds__(256) void k_sage_scatter(const float* __restrict__ X,
                                                      const int* __restrict__ src,
                                                      const int* __restrict__ dst,
                                                      float* __restrict__ out, int E) {
    int e = blockIdx.x * 4 + threadIdx.y;
    if (e >= E) return;
    int s = src[e], d = dst[e];
    int f = threadIdx.x;
    atomicAdd(&out[(size_t)d * 64 + f], X[(size_t)s * 64 + f]);
}

// ---------------- pooling ----------------
__global__ void k_pool(const float* __restrict__ X, const int* __restrict__ batch,
                       float* __restrict__ pooled, int off, int n) {
    int idx = blockIdx.x * 256 + threadIdx.x;
    if (idx >= n * 64) return;
    int v = idx >> 6, f = idx & 63;
    atomicAdd(&pooled[batch[v] * 128 + off + f], X[idx]);
}

// ---------------- head MLP (single block) ----------------
__global__ __launch_bounds__(256) void k_head(const float* __restrict__ pooled,
                                              const int* __restrict__ gcnt,
                                              const float* __restrict__ P_,
                                              const int* __restrict__ flag,
                                              void* __restrict__ out) {
    const float* f1W = P_ + PW_F1W;
    const float* f1b = P_ + PW_F1B;
    const float* bn1 = P_ + PW_BN1;
    const float* f2W = P_ + PW_F2W;
    const float* f2b = P_ + PW_F2B;
    const float* bn2 = P_ + PW_BN2;
    const float* f3W = P_ + PW_F3W;
    const float* f3b = P_ + PW_F3B;
    __shared__ float P[64][128];
    __shared__ float Z1[64][64];
    __shared__ float Z2[64][32];
    int t = threadIdx.x;
    for (int i = t; i < 64 * 128; i += 256) {
        int g = i >> 7;
        float c = fmaxf((float)gcnt[g], 1.0f);
        P[g][i & 127] = pooled[i] / c;
    }
    __syncthreads();
    for (int o = t; o < 64 * 64; o += 256) {
        int g = o >> 6, f = o & 63;
        float acc = 0.0f;
        for (int c = 0; c < 128; ++c) acc = fmaf(P[g][c], f1W[c * 64 + f], acc);
        float y = acc + f1b[f];
        y = (y - bn1[128 + f]) * rsqrtf(bn1[192 + f] + EPSV) * bn1[f] + bn1[64 + f];
        Z1[g][f] = fmaxf(y, 0.0f);
    }
    __syncthreads();
    for (int o = t; o < 64 * 32; o += 256) {
        int g = o >> 5, f = o & 31;
        float acc = 0.0f;
        for (int c = 0; c < 64; ++c) acc = fmaf(Z1[g][c], f2W[c * 32 + f], acc);
        float y = acc + f2b[f];
        y = (y - bn2[64 + f]) * rsqrtf(bn2[96 + f] + EPSV) * bn2[f] + bn2[32 + f];
        Z2[g][f] = fmaxf(y, 0.0f);
    }
    __syncthreads();
    if (t < 64) {
        float acc = 0.0f;
        for (int c = 0; c < 32; ++c) acc = fmaf(Z2[t][c], f3W[c], acc);
        float y = acc + f3b[0];
        if (*flag) ((__hip_bfloat16*)out)[t] = __float2bfloat16(y);  // bf16 dataset
        else       ((float*)out)[t] = y;                              // fp32 dataset
    }
}

extern "C" void kernel_launch(void* const* d_in, const int* in_sizes, int n_in,
                              void* d_out, int out_size, void* d_ws, size_t ws_size,
                              hipStream_t stream) {
    (void)in_sizes; (void)n_in; (void)out_size; (void)ws_size;
    const void* x     = d_in[0];
    const int*  eidx  = (const int*)d_in[1];
    const int*  batch = (const int*)d_in[2];

    const int n = NN, E = NE;
    const int* src = eidx;
    const int* dst = eidx + E;

    char* w = (char*)d_ws;
    float* h   = (float*)w;  w += (size_t)n * 64 * 4;
    float* bA  = (float*)w;  w += (size_t)n * 64 * 4;
    float* bB  = (float*)w;  w += (size_t)n * 64 * 4;
    int*   indeg = (int*)w;  w += (size_t)n * 4;
    float* dinv  = (float*)w; w += (size_t)n * 4;
    float* cinv  = (float*)w; w += (size_t)n * 4;
    int*   gcnt  = (int*)w;  w += 64 * 4;
    float* pooled = (float*)w; w += 64 * 128 * 4;
    int*   cnt   = (int*)w;  w += 8;
    int*   flag  = (int*)w;  w += 8;           // keep params 16B-aligned
    float* prm   = (float*)w;                  // PW_TOT floats

    hipMemsetAsync(indeg, 0, (size_t)n * 4, stream);
    hipMemsetAsync(gcnt, 0, 64 * 4 + 64 * 128 * 4, stream);  // gcnt + pooled contiguous
    hipMemsetAsync(cnt, 0, 4, stream);

    dim3 b256(256);

    // dtype detection on x (first 256K uint16 halves)
    const int DETN = 262144;
    k_detect<<<dim3(DETN / 256), b256, 0, stream>>>((const unsigned short*)x, cnt, DETN);
    k_resolve<<<1, 64, 0, stream>>>(cnt, flag);

    // convert all params to fp32
    PSrc ps;
    for (int i = 0; i < 17; ++i) ps.p[i] = d_in[3 + i];
    k_cvt<<<dim3((PW_TOT + 255) / 256), b256, 0, stream>>>(ps, flag, prm);

    k_degree<<<dim3((E + 255) / 256), b256, 0, stream>>>(dst, indeg, E);
    k_gcount<<<dim3((n + 255) / 256), b256, 0, stream>>>(batch, gcnt, n);
    k_prep<<<dim3((n + 255) / 256), b256, 0, stream>>>(indeg, dinv, cinv, n);

    int gGemm = (n + 63) / 64;
    dim3 bScat(64, 4);
    int gScat = (E + 3) / 4;
    int gEW = (n * 64 + 255) / 256;

    k_in_gemm<<<gGemm, b256, 0, stream>>>(x, prm + PW_WIN, prm + PW_BIN, flag, h, n);

    // GCN layer 0: h -> T=bA, agg init bB; scatter; post -> bA   (h preserved)
    k_gcn_gemm<<<gGemm, b256, 0, stream>>>(h, prm + PW_GCNW, dinv, bA, bB, n);
    k_gcn_scatter<<<gScat, bScat, 0, stream>>>(bA, dinv, src, dst, bB, E);
    k_gcn_post<<<gEW, b256, 0, stream>>>(bB, dinv, prm + PW_GCNB, prm + PW_GCNBN, bA, n);
    // GCN layer 1: bA -> T in-place bA, agg init bB; scatter; post -> bA
    k_gcn_gemm<<<gGemm, b256, 0, stream>>>(bA, prm + PW_GCNW + 4096, dinv, bA, bB, n);
    k_gcn_scatter<<<gScat, bScat, 0, stream>>>(bA, dinv, src, dst, bB, E);
    k_gcn_post<<<gEW, b256, 0, stream>>>(bB, dinv, prm + PW_GCNB + 64, prm + PW_GCNBN + 256, bA, n);
    k_pool<<<gEW, b256, 0, stream>>>(bA, batch, pooled, 0, n);

    // SAGE layer 0: agg(h) -> bB, combine -> bA (bA free after pool)
    hipMemsetAsync(bB, 0, (size_t)n * 64 * 4, stream);
    k_sage_scatter<<<gScat, bScat, 0, stream>>>(h, src, dst, bB, E);
    k_sage_gemm<<<gGemm, b256, 0, stream>>>(bB, h, prm + PW_SWL, prm + PW_SWR,
                                            prm + PW_SB, prm + PW_SBN, cinv, bA, n);
    // SAGE layer 1: agg(bA) -> bB, combine -> h (h free now)
    hipMemsetAsync(bB, 0, (size_t)n * 64 * 4, stream);
    k_sage_scatter<<<gScat, bScat, 0, stream>>>(bA, src, dst, bB, E);
    k_sage_gemm<<<gGemm, b256, 0, stream>>>(bB, bA, prm + PW_SWL + 4096, prm + PW_SWR + 4096,
                                            prm + PW_SB + 64, prm + PW_SBN + 256, cinv, h, n);
    k_pool<<<gEW, b256, 0, stream>>>(h, batch, pooled, 64, n);

    k_head<<<1, b256, 0, stream>>>(pooled, gcnt, prm, flag, d_out);
}

// Round 4
// 854.419 us; speedup vs baseline: 1.9310x; 1.9310x over previous
//
#include <hip/hip_runtime.h>
#include <hip/hip_bf16.h>

#define NN 50000
#define NE 1200000
#define DIN 128
#define HDIM 64
#define NG 64
#define EPSV 1e-5f

__device__ __forceinline__ float b2f(const __hip_bfloat16 v) { return __bfloat162float(v); }

// dual-dtype load: isbf16 selects interpretation of the raw input pointer
__device__ __forceinline__ float ldf(const void* p, size_t idx, int isbf16) {
    return isbf16 ? b2f(((const __hip_bfloat16*)p)[idx]) : ((const float*)p)[idx];
}

// ---------------- dtype detection ----------------
__global__ void k_detect(const unsigned short* __restrict__ x, int* __restrict__ cnt, int n) {
    int i = blockIdx.x * 256 + threadIdx.x;
    if (i < n) {
        unsigned short u = x[i];
        if (((u >> 7) & 0xFF) == 0xFF) atomicAdd(cnt, 1);
    }
}

// flag = 1 if bf16, 0 if fp32
__global__ void k_resolve(const int* __restrict__ cnt, int* __restrict__ flag) {
    if (threadIdx.x == 0 && blockIdx.x == 0) *flag = (*cnt < 4) ? 1 : 0;
}

// ---------------- param conversion into fp32 workspace ----------------
#define PW_WIN   0
#define PW_BIN   8192
#define PW_GCNW  8256
#define PW_GCNB  16448
#define PW_GCNBN 16576
#define PW_SWL   17088
#define PW_SWR   25280
#define PW_SB    33472
#define PW_SBN   33600
#define PW_F1W   34112
#define PW_F1B   42304
#define PW_BN1   42368
#define PW_F2W   42624
#define PW_F2B   44672
#define PW_BN2   44704
#define PW_F3W   44832
#define PW_F3B   44864
#define PW_TOT   44865

struct PSrc { const void* p[17]; };

__global__ void k_cvt(PSrc s, const int* __restrict__ flag, float* __restrict__ dst) {
    const int offs[18] = {PW_WIN, PW_BIN, PW_GCNW, PW_GCNB, PW_GCNBN, PW_SWL, PW_SWR,
                          PW_SB, PW_SBN, PW_F1W, PW_F1B, PW_BN1, PW_F2W, PW_F2B,
                          PW_BN2, PW_F3W, PW_F3B, PW_TOT};
    int i = blockIdx.x * 256 + threadIdx.x;
    if (i >= PW_TOT) return;
    int f = *flag;
    int seg = 0;
    while (i >= offs[seg + 1]) ++seg;
    dst[i] = ldf(s.p[seg], i - offs[seg], f);
}

// ---------------- CSR build ----------------
__global__ void k_degree(const int* __restrict__ dst, int* __restrict__ indeg, int E) {
    int e = blockIdx.x * 256 + threadIdx.x;
    if (e < E) atomicAdd(&indeg[dst[e]], 1);
}

__global__ void k_gcount(const int* __restrict__ batch, int* __restrict__ gcnt, int n) {
    int v = blockIdx.x * 256 + threadIdx.x;
    if (v < n) atomicAdd(&gcnt[batch[v]], 1);
}

// single-block exclusive scan of indeg -> rowptr; also emits dinv/cinv
__global__ __launch_bounds__(1024) void k_scan(const int* __restrict__ indeg,
                                               int* __restrict__ rowptr,
                                               float* __restrict__ dinv,
                                               float* __restrict__ cinv, int n) {
    __shared__ int buf[1024];
    int t = threadIdx.x;
    int carry = 0;
    for (int base = 0; base < n; base += 1024) {
        int i = base + t;
        int d = (i < n) ? indeg[i] : 0;
        if (i < n) {
            float fd = (float)d;
            dinv[i] = rsqrtf(fd + 1.0f);        // GCN deg includes self-loop
            cinv[i] = 1.0f / fmaxf(fd, 1.0f);   // SAGE mean denominator
        }
        buf[t] = d;
        __syncthreads();
        for (int off = 1; off < 1024; off <<= 1) {
            int x = (t >= off) ? buf[t - off] : 0;
            __syncthreads();
            buf[t] += x;
            __syncthreads();
        }
        if (i < n) rowptr[i] = carry + buf[t] - d;   // exclusive
        int tot = buf[1023];
        __syncthreads();
        carry += tot;
    }
    if (t == 0) rowptr[n] = carry;
}

__global__ void k_fill(const int* __restrict__ src, const int* __restrict__ dst,
                       const int* __restrict__ rowptr, int* __restrict__ cursor,
                       int* __restrict__ csr_src, int E) {
    int e = blockIdx.x * 256 + threadIdx.x;
    if (e < E) {
        int d = dst[e];
        int slot = rowptr[d] + atomicAdd(&cursor[d], 1);
        csr_src[slot] = src[e];
    }
}

// ---------------- tiled GEMM helpers (64x64 tile, 256 threads) ----------------
__device__ __forceinline__ void mac16(float acc[4][4], const float4 av, const float4 wv) {
    float a[4] = {av.x, av.y, av.z, av.w};
    float w[4] = {wv.x, wv.y, wv.z, wv.w};
#pragma unroll
    for (int i = 0; i < 4; i++)
#pragma unroll
        for (int j = 0; j < 4; j++) acc[i][j] = fmaf(a[i], w[j], acc[i][j]);
}

// h = relu(x @ W_in + b_in)
__global__ __launch_bounds__(256) void k_in_gemm(const void* __restrict__ A,
                                                 const float* __restrict__ W,
                                                 const float* __restrict__ bias,
                                                 const int* __restrict__ flag,
                                                 float* __restrict__ out, int n) {
    __shared__ float As[64][68];
    __shared__ float Ws[64][64];
    int t = threadIdx.x;
    int v0 = blockIdx.x * 64;
    int tx = t & 15, ty = t >> 4;
    int f16 = *flag;
    float acc[4][4] = {};
    for (int k0 = 0; k0 < 128; k0 += 64) {
#pragma unroll
        for (int j = 0; j < 16; ++j) {
            int i = t + 256 * j;
            int r = i >> 6, k = i & 63;
            int v = v0 + r;
            As[k][r] = (v < n) ? ldf(A, (size_t)v * DIN + k0 + k, f16) : 0.0f;
        }
#pragma unroll
        for (int j = 0; j < 16; ++j) {
            int i = t + 256 * j;
            int kk = i >> 6, f = i & 63;
            Ws[kk][f] = W[(k0 + kk) * 64 + f];
        }
        __syncthreads();
#pragma unroll 8
        for (int k = 0; k < 64; ++k) {
            float4 wv = *(const float4*)&Ws[k][tx * 4];
            float4 av = *(const float4*)&As[k][ty * 4];
            mac16(acc, av, wv);
        }
        __syncthreads();
    }
#pragma unroll
    for (int i = 0; i < 4; i++) {
        int v = v0 + ty * 4 + i;
        if (v < n) {
#pragma unroll
            for (int j = 0; j < 4; j++) {
                int f = tx * 4 + j;
                out[(size_t)v * 64 + f] = fmaxf(acc[i][j] + bias[f], 0.0f);
            }
        }
    }
}

// T = A @ W (plain)
__global__ __launch_bounds__(256) void k_gcn_gemm(const float* __restrict__ A,
                                                  const float* __restrict__ W,
                                                  float* __restrict__ T, int n) {
    __shared__ float As[64][68];
    __shared__ float Ws[64][64];
    int t = threadIdx.x;
    int v0 = blockIdx.x * 64;
    int tx = t & 15, ty = t >> 4;
    float acc[4][4] = {};
#pragma unroll
    for (int j = 0; j < 16; ++j) {
        int i = t + 256 * j;
        int r = i >> 6, k = i & 63;
        int v = v0 + r;
        As[k][r] = (v < n) ? A[(size_t)v * 64 + k] : 0.0f;
    }
#pragma unroll
    for (int j = 0; j < 16; ++j) {
        int i = t + 256 * j;
        int kk = i >> 6, f = i & 63;
        Ws[kk][f] = W[kk * 64 + f];
    }
    __syncthreads();
#pragma unroll 8
    for (int k = 0; k < 64; ++k) {
        float4 wv = *(const float4*)&Ws[k][tx * 4];
        float4 av = *(const float4*)&As[k][ty * 4];
        mac16(acc, av, wv);
    }
#pragma unroll
    for (int i = 0; i < 4; i++) {
        int v = v0 + ty * 4 + i;
        if (v < n) {
#pragma unroll
            for (int j = 0; j < 4; j++) {
                int f = tx * 4 + j;
                T[(size_t)v * 64 + f] = acc[i][j];
            }
        }
    }
}

// out = relu(bn( (mean_agg) @ Wl + X @ Wr + b ))   (AGG already mean-scaled)
__global__ __launch_bounds__(256) void k_sage_gemm(const float* __restrict__ AGG,
                                                   const float* __restrict__ X,
                                                   const float* __restrict__ Wl,
                                                   const float* __restrict__ Wr,
                                                   const float* __restrict__ bias,
                                                   const float* __restrict__ bn,
                                                   float* __restrict__ out, int n) {
    __shared__ float As[64][68];
    __shared__ float Ws[64][64];
    int t = threadIdx.x;
    int v0 = blockIdx.x * 64;
    int tx = t & 15, ty = t >> 4;
    float acc[4][4] = {};
    for (int pass = 0; pass < 2; ++pass) {
        const float* Ap = pass ? X : AGG;
        const float* Wp = pass ? Wr : Wl;
#pragma unroll
        for (int j = 0; j < 16; ++j) {
            int i = t + 256 * j;
            int r = i >> 6, k = i & 63;
            int v = v0 + r;
            As[k][r] = (v < n) ? Ap[(size_t)v * 64 + k] : 0.0f;
        }
#pragma unroll
        for (int j = 0; j < 16; ++j) {
            int i = t + 256 * j;
            int kk = i >> 6, f = i & 63;
            Ws[kk][f] = Wp[kk * 64 + f];
        }
        __syncthreads();
#pragma unroll 8
        for (int k = 0; k < 64; ++k) {
            float4 wv = *(const float4*)&Ws[k][tx * 4];
            float4 av = *(const float4*)&As[k][ty * 4];
            mac16(acc, av, wv);
        }
        __syncthreads();
    }
#pragma unroll
    for (int i = 0; i < 4; i++) {
        int v = v0 + ty * 4 + i;
        if (v < n) {
#pragma unroll
            for (int j = 0; j < 4; j++) {
                int f = tx * 4 + j;
                float y = acc[i][j] + bias[f];
                y = (y - bn[128 + f]) * rsqrtf(bn[192 + f] + EPSV) * bn[f] + bn[64 + f];
                out[(size_t)v * 64 + f] = fmaxf(y, 0.0f);
            }
        }
    }
}

// ---------------- CSR gather aggregations (1 wave = 1 node, lane = feature) -------------
// GCN: y = relu(bn( dinv[v]*( T[v]*dinv[v] + sum_s T[s]*dinv[s] ) + b ))
__global__ __launch_bounds__(256) void k_gcn_gather(const float* __restrict__ T,
                                                    const float* __restrict__ dinv,
                                                    const int* __restrict__ rowptr,
                                                    const int* __restrict__ csr_src,
                                                    const float* __restrict__ bias,
                                                    const float* __restrict__ bn,
                                                    float* __restrict__ out, int n) {
    int wid = threadIdx.x >> 6, lane = threadIdx.x & 63;
    int v = blockIdx.x * 4 + wid;
    if (v >= n) return;
    int beg = rowptr[v], end = rowptr[v + 1];
    float dv = dinv[v];
    float acc = T[(size_t)v * 64 + lane] * dv;
    int i = beg;
    for (; i + 4 <= end; i += 4) {
        int s0 = csr_src[i], s1 = csr_src[i + 1], s2 = csr_src[i + 2], s3 = csr_src[i + 3];
        float w0 = dinv[s0], w1 = dinv[s1], w2 = dinv[s2], w3 = dinv[s3];
        float x0 = T[(size_t)s0 * 64 + lane], x1 = T[(size_t)s1 * 64 + lane];
        float x2 = T[(size_t)s2 * 64 + lane], x3 = T[(size_t)s3 * 64 + lane];
        acc = fmaf(x0, w0, acc); acc = fmaf(x1, w1, acc);
        acc = fmaf(x2, w2, acc); acc = fmaf(x3, w3, acc);
    }
    for (; i < end; ++i) {
        int s = csr_src[i];
        acc = fmaf(T[(size_t)s * 64 + lane], dinv[s], acc);
    }
    float y = dv * acc + bias[lane];
    y = (y - bn[128 + lane]) * rsqrtf(bn[192 + lane] + EPSV) * bn[lane] + bn[64 + lane];
    out[(size_t)v * 64 + lane] = fmaxf(y, 0.0f);
}

// SAGE: out = mean of in-neighbors = cinv[v] * sum_s X[s]
__global__ __launch_bounds__(256) void k_sage_gather(const float* __restrict__ X,
                                                     const float* __restrict__ cinv,
                                                     const int* __restrict__ rowptr,
                                                     const int* __restrict__ csr_src,
                                                     float* __restrict__ out, int n) {
    int wid = threadIdx.x >> 6, lane = threadIdx.x & 63;
    int v = blockIdx.x * 4 + wid;
    if (v >= n) return;
    int beg = rowptr[v], end = rowptr[v + 1];
    float acc = 0.0f;
    int i = beg;
    for (; i + 4 <= end; i += 4) {
        int s0 = csr_src[i], s1 = csr_src[i + 1], s2 = csr_src[i + 2], s3 = csr_src[i + 3];
        acc += X[(size_t)s0 * 64 + lane] + X[(size_t)s1 * 64 + lane]
             + X[(size_t)s2 * 64 + lane] + X[(size_t)s3 * 64 + lane];
    }
    for (; i < end; ++i) acc += X[(size_t)csr_src[i] * 64 + lane];
    out[(size_t)v * 64 + lane] = acc * cinv[v];
}

// ---------------- pooling: wave run-length accumulate over sorted batch ----------------
__global__ __launch_bounds__(256) void k_pool(const float* __restrict__ X,
                                              const int* __restrict__ batch,
                                              float* __restrict__ pooled, int off, int n) {
    int wid = threadIdx.x >> 6, lane = threadIdx.x & 63;
    int v0 = blockIdx.x * 64 + wid * 16;
    float acc = 0.0f;
    int g = -1;
    for (int j = 0; j < 16; ++j) {
        int v = v0 + j;
        if (v >= n) break;
        int b = batch[v];
        if (b != g) {
            if (g >= 0) atomicAdd(&pooled[g * 128 + off + lane], acc);
            g = b; acc = 0.0f;
        }
        acc += X[(size_t)v * 64 + lane];
    }
    if (g >= 0) atomicAdd(&pooled[g * 128 + off + lane], acc);
}

// ---------------- head MLP (single block) ----------------
__global__ __launch_bounds__(256) void k_head(const float* __restrict__ pooled,
                                              const int* __restrict__ gcnt,
                                              const float* __restrict__ P_,
                                              const int* __restrict__ flag,
                                              void* __restrict__ out) {
    const float* f1W = P_ + PW_F1W;
    const float* f1b = P_ + PW_F1B;
    const float* bn1 = P_ + PW_BN1;
    const float* f2W = P_ + PW_F2W;
    const float* f2b = P_ + PW_F2B;
    const float* bn2 = P_ + PW_BN2;
    const float* f3W = P_ + PW_F3W;
    const float* f3b = P_ + PW_F3B;
    __shared__ float P[64][128];
    __shared__ float Z1[64][64];
    __shared__ float Z2[64][32];
    int t = threadIdx.x;
    for (int i = t; i < 64 * 128; i += 256) {
        int g = i >> 7;
        float c = fmaxf((float)gcnt[g], 1.0f);
        P[g][i & 127] = pooled[i] / c;
    }
    __syncthreads();
    for (int o = t; o < 64 * 64; o += 256) {
        int g = o >> 6, f = o & 63;
        float acc = 0.0f;
        for (int c = 0; c < 128; ++c) acc = fmaf(P[g][c], f1W[c * 64 + f], acc);
        float y = acc + f1b[f];
        y = (y - bn1[128 + f]) * rsqrtf(bn1[192 + f] + EPSV) * bn1[f] + bn1[64 + f];
        Z1[g][f] = fmaxf(y, 0.0f);
    }
    __syncthreads();
    for (int o = t; o < 64 * 32; o += 256) {
        int g = o >> 5, f = o & 31;
        float acc = 0.0f;
        for (int c = 0; c < 64; ++c) acc = fmaf(Z1[g][c], f2W[c * 32 + f], acc);
        float y = acc + f2b[f];
        y = (y - bn2[64 + f]) * rsqrtf(bn2[96 + f] + EPSV) * bn2[f] + bn2[32 + f];
        Z2[g][f] = fmaxf(y, 0.0f);
    }
    __syncthreads();
    if (t < 64) {
        float acc = 0.0f;
        for (int c = 0; c < 32; ++c) acc = fmaf(Z2[t][c], f3W[c], acc);
        float y = acc + f3b[0];
        if (*flag) ((__hip_bfloat16*)out)[t] = __float2bfloat16(y);  // bf16 dataset
        else       ((float*)out)[t] = y;                              // fp32 dataset
    }
}

extern "C" void kernel_launch(void* const* d_in, const int* in_sizes, int n_in,
                              void* d_out, int out_size, void* d_ws, size_t ws_size,
                              hipStream_t stream) {
    (void)in_sizes; (void)n_in; (void)out_size; (void)ws_size;
    const void* x     = d_in[0];
    const int*  eidx  = (const int*)d_in[1];
    const int*  batch = (const int*)d_in[2];

    const int n = NN, E = NE;
    const int* src = eidx;
    const int* dst = eidx + E;

    char* w = (char*)d_ws;
    float* h   = (float*)w;  w += (size_t)n * 64 * 4;
    float* bA  = (float*)w;  w += (size_t)n * 64 * 4;
    float* bB  = (float*)w;  w += (size_t)n * 64 * 4;
    int*   indeg  = (int*)w;  w += (size_t)n * 4;
    int*   cursor = (int*)w;  w += (size_t)n * 4;
    int*   rowptr = (int*)w;  w += (size_t)(n + 8) * 4;
    int*   csr_src = (int*)w; w += (size_t)E * 4;
    float* dinv  = (float*)w; w += (size_t)n * 4;
    float* cinv  = (float*)w; w += (size_t)n * 4;
    int*   gcnt  = (int*)w;  w += 64 * 4;
    float* pooled = (float*)w; w += 64 * 128 * 4;
    int*   cnt   = (int*)w;  w += 8;
    int*   flag  = (int*)w;  w += 8;
    float* prm   = (float*)w;                  // PW_TOT floats

    hipMemsetAsync(indeg, 0, (size_t)n * 8, stream);         // indeg + cursor contiguous
    hipMemsetAsync(gcnt, 0, 64 * 4 + 64 * 128 * 4, stream);  // gcnt + pooled contiguous
    hipMemsetAsync(cnt, 0, 4, stream);

    dim3 b256(256);

    // dtype detection + param conversion
    const int DETN = 262144;
    k_detect<<<dim3(DETN / 256), b256, 0, stream>>>((const unsigned short*)x, cnt, DETN);
    k_resolve<<<1, 64, 0, stream>>>(cnt, flag);
    PSrc ps;
    for (int i = 0; i < 17; ++i) ps.p[i] = d_in[3 + i];
    k_cvt<<<dim3((PW_TOT + 255) / 256), b256, 0, stream>>>(ps, flag, prm);

    // CSR build
    k_degree<<<dim3((E + 255) / 256), b256, 0, stream>>>(dst, indeg, E);
    k_scan<<<1, 1024, 0, stream>>>(indeg, rowptr, dinv, cinv, n);
    k_fill<<<dim3((E + 255) / 256), b256, 0, stream>>>(src, dst, rowptr, cursor, csr_src, E);
    k_gcount<<<dim3((n + 255) / 256), b256, 0, stream>>>(batch, gcnt, n);

    int gGemm = (n + 63) / 64;
    int gGath = (n + 3) / 4;
    int gPool = (n + 63) / 64;

    k_in_gemm<<<gGemm, b256, 0, stream>>>(x, prm + PW_WIN, prm + PW_BIN, flag, h, n);

    // GCN layer 0: h -> T(bA); gather+bn+relu -> bB
    k_gcn_gemm<<<gGemm, b256, 0, stream>>>(h, prm + PW_GCNW, bA, n);
    k_gcn_gather<<<gGath, b256, 0, stream>>>(bA, dinv, rowptr, csr_src,
                                             prm + PW_GCNB, prm + PW_GCNBN, bB, n);
    // GCN layer 1: bB -> T(bA); gather -> bB (final GCN features)
    k_gcn_gemm<<<gGemm, b256, 0, stream>>>(bB, prm + PW_GCNW + 4096, bA, n);
    k_gcn_gather<<<gGath, b256, 0, stream>>>(bA, dinv, rowptr, csr_src,
                                             prm + PW_GCNB + 64, prm + PW_GCNBN + 256, bB, n);
    k_pool<<<gPool, b256, 0, stream>>>(bB, batch, pooled, 0, n);

    // SAGE layer 0: mean-gather(h) -> bA; gemm(bA, h) -> bB
    k_sage_gather<<<gGath, b256, 0, stream>>>(h, cinv, rowptr, csr_src, bA, n);
    k_sage_gemm<<<gGemm, b256, 0, stream>>>(bA, h, prm + PW_SWL, prm + PW_SWR,
                                            prm + PW_SB, prm + PW_SBN, bB, n);
    // SAGE layer 1: mean-gather(bB) -> bA; gemm(bA, bB) -> h
    k_sage_gather<<<gGath, b256, 0, stream>>>(bB, cinv, rowptr, csr_src, bA, n);
    k_sage_gemm<<<gGemm, b256, 0, stream>>>(bA, bB, prm + PW_SWL + 4096, prm + PW_SWR + 4096,
                                            prm + PW_SB + 64, prm + PW_SBN + 256, h, n);
    k_pool<<<gPool, b256, 0, stream>>>(h, batch, pooled, 64, n);

    k_head<<<1, b256, 0, stream>>>(pooled, gcnt, prm, flag, d_out);
}

// Round 5
// 667.193 us; speedup vs baseline: 2.4729x; 1.2806x over previous
//
#include <hip/hip_runtime.h>
#include <hip/hip_bf16.h>

#define NN 50000
#define NE 1200000
#define DIN 128
#define HDIM 64
#define NG 64
#define EPSV 1e-5f

__device__ __forceinline__ float b2f(const __hip_bfloat16 v) { return __bfloat162float(v); }

// dual-dtype load: isbf16 selects interpretation of the raw input pointer
__device__ __forceinline__ float ldf(const void* p, size_t idx, int isbf16) {
    return isbf16 ? b2f(((const __hip_bfloat16*)p)[idx]) : ((const float*)p)[idx];
}

// ---------------- dtype detection ----------------
__global__ void k_detect(const unsigned short* __restrict__ x, int* __restrict__ cnt, int n) {
    int i = blockIdx.x * 256 + threadIdx.x;
    if (i < n) {
        unsigned short u = x[i];
        if (((u >> 7) & 0xFF) == 0xFF) atomicAdd(cnt, 1);
    }
}

// flag = 1 if bf16, 0 if fp32
__global__ void k_resolve(const int* __restrict__ cnt, int* __restrict__ flag) {
    if (threadIdx.x == 0 && blockIdx.x == 0) *flag = (*cnt < 4) ? 1 : 0;
}

// ---------------- param conversion into fp32 workspace ----------------
#define PW_WIN   0
#define PW_BIN   8192
#define PW_GCNW  8256
#define PW_GCNB  16448
#define PW_GCNBN 16576
#define PW_SWL   17088
#define PW_SWR   25280
#define PW_SB    33472
#define PW_SBN   33600
#define PW_F1W   34112
#define PW_F1B   42304
#define PW_BN1   42368
#define PW_F2W   42624
#define PW_F2B   44672
#define PW_BN2   44704
#define PW_F3W   44832
#define PW_F3B   44864
#define PW_TOT   44865

struct PSrc { const void* p[17]; };

__global__ void k_cvt(PSrc s, const int* __restrict__ flag, float* __restrict__ dst) {
    const int offs[18] = {PW_WIN, PW_BIN, PW_GCNW, PW_GCNB, PW_GCNBN, PW_SWL, PW_SWR,
                          PW_SB, PW_SBN, PW_F1W, PW_F1B, PW_BN1, PW_F2W, PW_F2B,
                          PW_BN2, PW_F3W, PW_F3B, PW_TOT};
    int i = blockIdx.x * 256 + threadIdx.x;
    if (i >= PW_TOT) return;
    int f = *flag;
    int seg = 0;
    while (i >= offs[seg + 1]) ++seg;
    dst[i] = ldf(s.p[seg], i - offs[seg], f);
}

// ---------------- CSR build ----------------
__global__ void k_degree(const int* __restrict__ dst, int* __restrict__ indeg, int E) {
    int e = blockIdx.x * 256 + threadIdx.x;
    if (e < E) atomicAdd(&indeg[dst[e]], 1);
}

// per-block LDS histogram: contended global atomics 50000 -> ~O(blocks*nonzero bins)
__global__ __launch_bounds__(256) void k_gcount(const int* __restrict__ batch,
                                                int* __restrict__ gcnt, int n) {
    __shared__ int hist[NG];
    int t = threadIdx.x;
    if (t < NG) hist[t] = 0;
    __syncthreads();
    int v = blockIdx.x * 1024 + t;
#pragma unroll
    for (int j = 0; j < 4; ++j, v += 256)
        if (v < n) atomicAdd(&hist[batch[v]], 1);
    __syncthreads();
    if (t < NG) {
        int c = hist[t];
        if (c) atomicAdd(&gcnt[t], c);
    }
}

// single-block exclusive scan of indeg -> rowptr (wave-shuffle based); emits dinv/cinv
__global__ __launch_bounds__(1024) void k_scan(const int* __restrict__ indeg,
                                               int* __restrict__ rowptr,
                                               float* __restrict__ dinv,
                                               float* __restrict__ cinv, int n) {
    __shared__ int wsum[16];
    __shared__ int carry_s;
    int t = threadIdx.x;
    int wid = t >> 6, lane = t & 63;
    if (t == 0) carry_s = 0;
    __syncthreads();
    for (int base = 0; base < n; base += 1024) {
        int i = base + t;
        int d = (i < n) ? indeg[i] : 0;
        if (i < n) {
            float fd = (float)d;
            dinv[i] = rsqrtf(fd + 1.0f);        // GCN deg includes self-loop
            cinv[i] = 1.0f / fmaxf(fd, 1.0f);   // SAGE mean denominator
        }
        // inclusive scan within wave (no barriers)
        int x = d;
#pragma unroll
        for (int off = 1; off < 64; off <<= 1) {
            int y = __shfl_up(x, off, 64);
            if (lane >= off) x += y;
        }
        if (lane == 63) wsum[wid] = x;
        __syncthreads();
        if (wid == 0) {  // scan the 16 wave totals (inclusive)
            int s = (lane < 16) ? wsum[lane] : 0;
#pragma unroll
            for (int off = 1; off < 16; off <<= 1) {
                int y = __shfl_up(s, off, 64);
                if (lane >= off) s += y;
            }
            if (lane < 16) wsum[lane] = s;
        }
        __syncthreads();
        int waveoff = (wid > 0) ? wsum[wid - 1] : 0;
        int incl = carry_s + waveoff + x;       // inclusive global scan value
        if (i < n) rowptr[i] = incl - d;        // exclusive
        __syncthreads();                         // everyone has read carry_s
        if (t == 1023) carry_s = incl;          // chunk total
        __syncthreads();
    }
    if (t == 0) rowptr[n] = carry_s;
}

__global__ void k_fill(const int* __restrict__ src, const int* __restrict__ dst,
                       const int* __restrict__ rowptr, int* __restrict__ cursor,
                       int* __restrict__ csr_src, int E) {
    int e = blockIdx.x * 256 + threadIdx.x;
    if (e < E) {
        int d = dst[e];
        int slot = rowptr[d] + atomicAdd(&cursor[d], 1);
        csr_src[slot] = src[e];
    }
}

// ---------------- tiled GEMM helpers (64x64 tile, 256 threads) ----------------
__device__ __forceinline__ void mac16(float acc[4][4], const float4 av, const float4 wv) {
    float a[4] = {av.x, av.y, av.z, av.w};
    float w[4] = {wv.x, wv.y, wv.z, wv.w};
#pragma unroll
    for (int i = 0; i < 4; i++)
#pragma unroll
        for (int j = 0; j < 4; j++) acc[i][j] = fmaf(a[i], w[j], acc[i][j]);
}

// h = relu(x @ W_in + b_in)
__global__ __launch_bounds__(256) void k_in_gemm(const void* __restrict__ A,
                                                 const float* __restrict__ W,
                                                 const float* __restrict__ bias,
                                                 const int* __restrict__ flag,
                                                 float* __restrict__ out, int n) {
    __shared__ float As[64][68];
    __shared__ float Ws[64][64];
    int t = threadIdx.x;
    int v0 = blockIdx.x * 64;
    int tx = t & 15, ty = t >> 4;
    int f16 = *flag;
    float acc[4][4] = {};
    for (int k0 = 0; k0 < 128; k0 += 64) {
#pragma unroll
        for (int j = 0; j < 16; ++j) {
            int i = t + 256 * j;
            int r = i >> 6, k = i & 63;
            int v = v0 + r;
            As[k][r] = (v < n) ? ldf(A, (size_t)v * DIN + k0 + k, f16) : 0.0f;
        }
#pragma unroll
        for (int j = 0; j < 16; ++j) {
            int i = t + 256 * j;
            int kk = i >> 6, f = i & 63;
            Ws[kk][f] = W[(k0 + kk) * 64 + f];
        }
        __syncthreads();
#pragma unroll 8
        for (int k = 0; k < 64; ++k) {
            float4 wv = *(const float4*)&Ws[k][tx * 4];
            float4 av = *(const float4*)&As[k][ty * 4];
            mac16(acc, av, wv);
        }
        __syncthreads();
    }
#pragma unroll
    for (int i = 0; i < 4; i++) {
        int v = v0 + ty * 4 + i;
        if (v < n) {
#pragma unroll
            for (int j = 0; j < 4; j++) {
                int f = tx * 4 + j;
                out[(size_t)v * 64 + f] = fmaxf(acc[i][j] + bias[f], 0.0f);
            }
        }
    }
}

// T = A @ W (plain)
__global__ __launch_bounds__(256) void k_gcn_gemm(const float* __restrict__ A,
                                                  const float* __restrict__ W,
                                                  float* __restrict__ T, int n) {
    __shared__ float As[64][68];
    __shared__ float Ws[64][64];
    int t = threadIdx.x;
    int v0 = blockIdx.x * 64;
    int tx = t & 15, ty = t >> 4;
    float acc[4][4] = {};
#pragma unroll
    for (int j = 0; j < 16; ++j) {
        int i = t + 256 * j;
        int r = i >> 6, k = i & 63;
        int v = v0 + r;
        As[k][r] = (v < n) ? A[(size_t)v * 64 + k] : 0.0f;
    }
#pragma unroll
    for (int j = 0; j < 16; ++j) {
        int i = t + 256 * j;
        int kk = i >> 6, f = i & 63;
        Ws[kk][f] = W[kk * 64 + f];
    }
    __syncthreads();
#pragma unroll 8
    for (int k = 0; k < 64; ++k) {
        float4 wv = *(const float4*)&Ws[k][tx * 4];
        float4 av = *(const float4*)&As[k][ty * 4];
        mac16(acc, av, wv);
    }
#pragma unroll
    for (int i = 0; i < 4; i++) {
        int v = v0 + ty * 4 + i;
        if (v < n) {
#pragma unroll
            for (int j = 0; j < 4; j++) {
                int f = tx * 4 + j;
                T[(size_t)v * 64 + f] = acc[i][j];
            }
        }
    }
}

// out = relu(bn( (mean_agg) @ Wl + X @ Wr + b ))   (AGG already mean-scaled)
__global__ __launch_bounds__(256) void k_sage_gemm(const float* __restrict__ AGG,
                                                   const float* __restrict__ X,
                                                   const float* __restrict__ Wl,
                                                   const float* __restrict__ Wr,
                                                   const float* __restrict__ bias,
                                                   const float* __restrict__ bn,
                                                   float* __restrict__ out, int n) {
    __shared__ float As[64][68];
    __shared__ float Ws[64][64];
    int t = threadIdx.x;
    int v0 = blockIdx.x * 64;
    int tx = t & 15, ty = t >> 4;
    float acc[4][4] = {};
    for (int pass = 0; pass < 2; ++pass) {
        const float* Ap = pass ? X : AGG;
        const float* Wp = pass ? Wr : Wl;
#pragma unroll
        for (int j = 0; j < 16; ++j) {
            int i = t + 256 * j;
            int r = i >> 6, k = i & 63;
            int v = v0 + r;
            As[k][r] = (v < n) ? Ap[(size_t)v * 64 + k] : 0.0f;
        }
#pragma unroll
        for (int j = 0; j < 16; ++j) {
            int i = t + 256 * j;
            int kk = i >> 6, f = i & 63;
            Ws[kk][f] = Wp[kk * 64 + f];
        }
        __syncthreads();
#pragma unroll 8
        for (int k = 0; k < 64; ++k) {
            float4 wv = *(const float4*)&Ws[k][tx * 4];
            float4 av = *(const float4*)&As[k][ty * 4];
            mac16(acc, av, wv);
        }
        __syncthreads();
    }
#pragma unroll
    for (int i = 0; i < 4; i++) {
        int v = v0 + ty * 4 + i;
        if (v < n) {
#pragma unroll
            for (int j = 0; j < 4; j++) {
                int f = tx * 4 + j;
                float y = acc[i][j] + bias[f];
                y = (y - bn[128 + f]) * rsqrtf(bn[192 + f] + EPSV) * bn[f] + bn[64 + f];
                out[(size_t)v * 64 + f] = fmaxf(y, 0.0f);
            }
        }
    }
}

// ---------------- CSR gather aggregations (1 wave = 1 node, lane = feature) -------------
// GCN: y = relu(bn( dinv[v]*( T[v]*dinv[v] + sum_s T[s]*dinv[s] ) + b ))
__global__ __launch_bounds__(256) void k_gcn_gather(const float* __restrict__ T,
                                                    const float* __restrict__ dinv,
                                                    const int* __restrict__ rowptr,
                                                    const int* __restrict__ csr_src,
                                                    const float* __restrict__ bias,
                                                    const float* __restrict__ bn,
                                                    float* __restrict__ out, int n) {
    int wid = threadIdx.x >> 6, lane = threadIdx.x & 63;
    int v = blockIdx.x * 4 + wid;
    if (v >= n) return;
    int beg = rowptr[v], end = rowptr[v + 1];
    float dv = dinv[v];
    float acc = T[(size_t)v * 64 + lane] * dv;
    int i = beg;
    for (; i + 4 <= end; i += 4) {
        int s0 = csr_src[i], s1 = csr_src[i + 1], s2 = csr_src[i + 2], s3 = csr_src[i + 3];
        float w0 = dinv[s0], w1 = dinv[s1], w2 = dinv[s2], w3 = dinv[s3];
        float x0 = T[(size_t)s0 * 64 + lane], x1 = T[(size_t)s1 * 64 + lane];
        float x2 = T[(size_t)s2 * 64 + lane], x3 = T[(size_t)s3 * 64 + lane];
        acc = fmaf(x0, w0, acc); acc = fmaf(x1, w1, acc);
        acc = fmaf(x2, w2, acc); acc = fmaf(x3, w3, acc);
    }
    for (; i < end; ++i) {
        int s = csr_src[i];
        acc = fmaf(T[(size_t)s * 64 + lane], dinv[s], acc);
    }
    float y = dv * acc + bias[lane];
    y = (y - bn[128 + lane]) * rsqrtf(bn[192 + lane] + EPSV) * bn[lane] + bn[64 + lane];
    out[(size_t)v * 64 + lane] = fmaxf(y, 0.0f);
}

// SAGE: out = mean of in-neighbors = cinv[v] * sum_s X[s]
__global__ __launch_bounds__(256) void k_sage_gather(const float* __restrict__ X,
                                                     const float* __restrict__ cinv,
                                                     const int* __restrict__ rowptr,
                                                     const int* __restrict__ csr_src,
                                                     float* __restrict__ out, int n) {
    int wid = threadIdx.x >> 6, lane = threadIdx.x & 63;
    int v = blockIdx.x * 4 + wid;
    if (v >= n) return;
    int beg = rowptr[v], end = rowptr[v + 1];
    float acc = 0.0f;
    int i = beg;
    for (; i + 4 <= end; i += 4) {
        int s0 = csr_src[i], s1 = csr_src[i + 1], s2 = csr_src[i + 2], s3 = csr_src[i + 3];
        acc += X[(size_t)s0 * 64 + lane] + X[(size_t)s1 * 64 + lane]
             + X[(size_t)s2 * 64 + lane] + X[(size_t)s3 * 64 + lane];
    }
    for (; i < end; ++i) acc += X[(size_t)csr_src[i] * 64 + lane];
    out[(size_t)v * 64 + lane] = acc * cinv[v];
}

// ---------------- pooling: wave run-length accumulate over sorted batch ----------------
__global__ __launch_bounds__(256) void k_pool(const float* __restrict__ X,
                                              const int* __restrict__ batch,
                                              float* __restrict__ pooled, int off, int n) {
    int wid = threadIdx.x >> 6, lane = threadIdx.x & 63;
    int v0 = blockIdx.x * 64 + wid * 16;
    float acc = 0.0f;
    int g = -1;
    for (int j = 0; j < 16; ++j) {
        int v = v0 + j;
        if (v >= n) break;
        int b = batch[v];
        if (b != g) {
            if (g >= 0) atomicAdd(&pooled[g * 128 + off + lane], acc);
            g = b; acc = 0.0f;
        }
        acc += X[(size_t)v * 64 + lane];
    }
    if (g >= 0) atomicAdd(&pooled[g * 128 + off + lane], acc);
}

// ---------------- head MLP (single block) ----------------
__global__ __launch_bounds__(256) void k_head(const float* __restrict__ pooled,
                                              const int* __restrict__ gcnt,
                                              const float* __restrict__ P_,
                                              const int* __restrict__ flag,
                                              void* __restrict__ out) {
    const float* f1W = P_ + PW_F1W;
    const float* f1b = P_ + PW_F1B;
    const float* bn1 = P_ + PW_BN1;
    const float* f2W = P_ + PW_F2W;
    const float* f2b = P_ + PW_F2B;
    const float* bn2 = P_ + PW_BN2;
    const float* f3W = P_ + PW_F3W;
    const float* f3b = P_ + PW_F3B;
    __shared__ float P[64][128];
    __shared__ float Z1[64][64];
    __shared__ float Z2[64][32];
    int t = threadIdx.x;
    for (int i = t; i < 64 * 128; i += 256) {
        int g = i >> 7;
        float c = fmaxf((float)gcnt[g], 1.0f);
        P[g][i & 127] = pooled[i] / c;
    }
    __syncthreads();
    for (int o = t; o < 64 * 64; o += 256) {
        int g = o >> 6, f = o & 63;
        float acc = 0.0f;
        for (int c = 0; c < 128; ++c) acc = fmaf(P[g][c], f1W[c * 64 + f], acc);
        float y = acc + f1b[f];
        y = (y - bn1[128 + f]) * rsqrtf(bn1[192 + f] + EPSV) * bn1[f] + bn1[64 + f];
        Z1[g][f] = fmaxf(y, 0.0f);
    }
    __syncthreads();
    for (int o = t; o < 64 * 32; o += 256) {
        int g = o >> 5, f = o & 31;
        float acc = 0.0f;
        for (int c = 0; c < 64; ++c) acc = fmaf(Z1[g][c], f2W[c * 32 + f], acc);
        float y = acc + f2b[f];
        y = (y - bn2[64 + f]) * rsqrtf(bn2[96 + f] + EPSV) * bn2[f] + bn2[32 + f];
        Z2[g][f] = fmaxf(y, 0.0f);
    }
    __syncthreads();
    if (t < 64) {
        float acc = 0.0f;
        for (int c = 0; c < 32; ++c) acc = fmaf(Z2[t][c], f3W[c], acc);
        float y = acc + f3b[0];
        if (*flag) ((__hip_bfloat16*)out)[t] = __float2bfloat16(y);  // bf16 dataset
        else       ((float*)out)[t] = y;                              // fp32 dataset
    }
}

extern "C" void kernel_launch(void* const* d_in, const int* in_sizes, int n_in,
                              void* d_out, int out_size, void* d_ws, size_t ws_size,
                              hipStream_t stream) {
    (void)in_sizes; (void)n_in; (void)out_size; (void)ws_size;
    const void* x     = d_in[0];
    const int*  eidx  = (const int*)d_in[1];
    const int*  batch = (const int*)d_in[2];

    const int n = NN, E = NE;
    const int* src = eidx;
    const int* dst = eidx + E;

    char* w = (char*)d_ws;
    float* h   = (float*)w;  w += (size_t)n * 64 * 4;
    float* bA  = (float*)w;  w += (size_t)n * 64 * 4;
    float* bB  = (float*)w;  w += (size_t)n * 64 * 4;
    int*   indeg  = (int*)w;  w += (size_t)n * 4;
    int*   cursor = (int*)w;  w += (size_t)n * 4;
    int*   rowptr = (int*)w;  w += (size_t)(n + 8) * 4;
    int*   csr_src = (int*)w; w += (size_t)E * 4;
    float* dinv  = (float*)w; w += (size_t)n * 4;
    float* cinv  = (float*)w; w += (size_t)n * 4;
    int*   gcnt  = (int*)w;  w += 64 * 4;
    float* pooled = (float*)w; w += 64 * 128 * 4;
    int*   cnt   = (int*)w;  w += 8;
    int*   flag  = (int*)w;  w += 8;
    float* prm   = (float*)w;                  // PW_TOT floats

    hipMemsetAsync(indeg, 0, (size_t)n * 8, stream);         // indeg + cursor contiguous
    hipMemsetAsync(gcnt, 0, 64 * 4 + 64 * 128 * 4, stream);  // gcnt + pooled contiguous
    hipMemsetAsync(cnt, 0, 4, stream);

    dim3 b256(256);

    // dtype detection + param conversion
    const int DETN = 262144;
    k_detect<<<dim3(DETN / 256), b256, 0, stream>>>((const unsigned short*)x, cnt, DETN);
    k_resolve<<<1, 64, 0, stream>>>(cnt, flag);
    PSrc ps;
    for (int i = 0; i < 17; ++i) ps.p[i] = d_in[3 + i];
    k_cvt<<<dim3((PW_TOT + 255) / 256), b256, 0, stream>>>(ps, flag, prm);

    // CSR build
    k_degree<<<dim3((E + 255) / 256), b256, 0, stream>>>(dst, indeg, E);
    k_scan<<<1, 1024, 0, stream>>>(indeg, rowptr, dinv, cinv, n);
    k_fill<<<dim3((E + 255) / 256), b256, 0, stream>>>(src, dst, rowptr, cursor, csr_src, E);
    k_gcount<<<dim3((n + 1023) / 1024), b256, 0, stream>>>(batch, gcnt, n);

    int gGemm = (n + 63) / 64;
    int gGath = (n + 3) / 4;
    int gPool = (n + 63) / 64;

    k_in_gemm<<<gGemm, b256, 0, stream>>>(x, prm + PW_WIN, prm + PW_BIN, flag, h, n);

    // GCN layer 0: h -> T(bA); gather+bn+relu -> bB
    k_gcn_gemm<<<gGemm, b256, 0, stream>>>(h, prm + PW_GCNW, bA, n);
    k_gcn_gather<<<gGath, b256, 0, stream>>>(bA, dinv, rowptr, csr_src,
                                             prm + PW_GCNB, prm + PW_GCNBN, bB, n);
    // GCN layer 1: bB -> T(bA); gather -> bB (final GCN features)
    k_gcn_gemm<<<gGemm, b256, 0, stream>>>(bB, prm + PW_GCNW + 4096, bA, n);
    k_gcn_gather<<<gGath, b256, 0, stream>>>(bA, dinv, rowptr, csr_src,
                                             prm + PW_GCNB + 64, prm + PW_GCNBN + 256, bB, n);
    k_pool<<<gPool, b256, 0, stream>>>(bB, batch, pooled, 0, n);

    // SAGE layer 0: mean-gather(h) -> bA; gemm(bA, h) -> bB
    k_sage_gather<<<gGath, b256, 0, stream>>>(h, cinv, rowptr, csr_src, bA, n);
    k_sage_gemm<<<gGemm, b256, 0, stream>>>(bA, h, prm + PW_SWL, prm + PW_SWR,
                                            prm + PW_SB, prm + PW_SBN, bB, n);
    // SAGE layer 1: mean-gather(bB) -> bA; gemm(bA, bB) -> h
    k_sage_gather<<<gGath, b256, 0, stream>>>(bB, cinv, rowptr, csr_src, bA, n);
    k_sage_gemm<<<gGemm, b256, 0, stream>>>(bA, bB, prm + PW_SWL + 4096, prm + PW_SWR + 4096,
                                            prm + PW_SB + 64, prm + PW_SBN + 256, h, n);
    k_pool<<<gPool, b256, 0, stream>>>(h, batch, pooled, 64, n);

    k_head<<<1, b256, 0, stream>>>(pooled, gcnt, prm, flag, d_out);
}

// Round 6
// 546.846 us; speedup vs baseline: 3.0171x; 1.2201x over previous
//
#include <hip/hip_runtime.h>
#include <hip/hip_bf16.h>

#define NN 50000
#define NE 1200000
#define DIN 128
#define HDIM 64
#define NG 64
#define EPSV 1e-5f

__device__ __forceinline__ float b2f(const __hip_bfloat16 v) { return __bfloat162float(v); }

__device__ __forceinline__ float ldf(const void* p, size_t idx, int isbf16) {
    return isbf16 ? b2f(((const __hip_bfloat16*)p)[idx]) : ((const float*)p)[idx];
}

// ---------------- dtype detection ----------------
__global__ void k_detect(const unsigned short* __restrict__ x, int* __restrict__ cnt, int n) {
    int i = blockIdx.x * 256 + threadIdx.x;
    if (i < n) {
        unsigned short u = x[i];
        if (((u >> 7) & 0xFF) == 0xFF) atomicAdd(cnt, 1);
    }
}

// flag = 1 if bf16, 0 if fp32
__global__ void k_resolve(const int* __restrict__ cnt, int* __restrict__ flag) {
    if (threadIdx.x == 0 && blockIdx.x == 0) *flag = (*cnt < 4) ? 1 : 0;
}

// ---------------- param conversion into fp32 workspace ----------------
#define PW_WIN   0
#define PW_BIN   8192
#define PW_GCNW  8256
#define PW_GCNB  16448
#define PW_GCNBN 16576
#define PW_SWL   17088
#define PW_SWR   25280
#define PW_SB    33472
#define PW_SBN   33600
#define PW_F1W   34112
#define PW_F1B   42304
#define PW_BN1   42368
#define PW_F2W   42624
#define PW_F2B   44672
#define PW_BN2   44704
#define PW_F3W   44832
#define PW_F3B   44864
#define PW_TOT   44865

struct PSrc { const void* p[17]; };

__global__ void k_cvt(PSrc s, const int* __restrict__ flag, float* __restrict__ dst) {
    const int offs[18] = {PW_WIN, PW_BIN, PW_GCNW, PW_GCNB, PW_GCNBN, PW_SWL, PW_SWR,
                          PW_SB, PW_SBN, PW_F1W, PW_F1B, PW_BN1, PW_F2W, PW_F2B,
                          PW_BN2, PW_F3W, PW_F3B, PW_TOT};
    int i = blockIdx.x * 256 + threadIdx.x;
    if (i >= PW_TOT) return;
    int f = *flag;
    int seg = 0;
    while (i >= offs[seg + 1]) ++seg;
    dst[i] = ldf(s.p[seg], i - offs[seg], f);
}

// ---------------- CSR build ----------------
// degree count; atomic return value = edge's rank within its dst bucket
__global__ void k_degree(const int* __restrict__ dst, int* __restrict__ indeg,
                         int* __restrict__ rank, int E) {
    int e = blockIdx.x * 256 + threadIdx.x;
    if (e < E) rank[e] = atomicAdd(&indeg[dst[e]], 1);
}

// per-block LDS histogram for graph sizes
__global__ __launch_bounds__(256) void k_gcount(const int* __restrict__ batch,
                                                int* __restrict__ gcnt, int n) {
    __shared__ int hist[NG];
    int t = threadIdx.x;
    if (t < NG) hist[t] = 0;
    __syncthreads();
    int v = blockIdx.x * 1024 + t;
#pragma unroll
    for (int j = 0; j < 4; ++j, v += 256)
        if (v < n) atomicAdd(&hist[batch[v]], 1);
    __syncthreads();
    if (t < NG) {
        int c = hist[t];
        if (c) atomicAdd(&gcnt[t], c);
    }
}

// single-block exclusive scan of indeg -> rowptr (wave-shuffle); emits dinv/cinv
__global__ __launch_bounds__(1024) void k_scan(const int* __restrict__ indeg,
                                               int* __restrict__ rowptr,
                                               float* __restrict__ dinv,
                                               float* __restrict__ cinv, int n) {
    __shared__ int wsum[16];
    __shared__ int carry_s;
    int t = threadIdx.x;
    int wid = t >> 6, lane = t & 63;
    if (t == 0) carry_s = 0;
    __syncthreads();
    for (int base = 0; base < n; base += 1024) {
        int i = base + t;
        int d = (i < n) ? indeg[i] : 0;
        if (i < n) {
            float fd = (float)d;
            dinv[i] = rsqrtf(fd + 1.0f);        // GCN deg includes self-loop
            cinv[i] = 1.0f / fmaxf(fd, 1.0f);   // SAGE mean denominator
        }
        int x = d;
#pragma unroll
        for (int off = 1; off < 64; off <<= 1) {
            int y = __shfl_up(x, off, 64);
            if (lane >= off) x += y;
        }
        if (lane == 63) wsum[wid] = x;
        __syncthreads();
        if (wid == 0) {
            int s = (lane < 16) ? wsum[lane] : 0;
#pragma unroll
            for (int off = 1; off < 16; off <<= 1) {
                int y = __shfl_up(s, off, 64);
                if (lane >= off) s += y;
            }
            if (lane < 16) wsum[lane] = s;
        }
        __syncthreads();
        int waveoff = (wid > 0) ? wsum[wid - 1] : 0;
        int incl = carry_s + waveoff + x;
        if (i < n) rowptr[i] = incl - d;
        __syncthreads();
        if (t == 1023) carry_s = incl;
        __syncthreads();
    }
    if (t == 0) rowptr[n] = carry_s;
}

// no atomics: slot = rowptr[dst] + precomputed rank
__global__ void k_fill(const int* __restrict__ src, const int* __restrict__ dst,
                       const int* __restrict__ rowptr, const int* __restrict__ rank,
                       int* __restrict__ csr_src, int E) {
    int e = blockIdx.x * 256 + threadIdx.x;
    if (e < E) {
        int d = dst[e];
        csr_src[rowptr[d] + rank[e]] = src[e];
    }
}

// ---------------- GEMM helpers ----------------
__device__ __forceinline__ void mac16(float acc[4][4], const float4 av, const float4 wv) {
    float a[4] = {av.x, av.y, av.z, av.w};
    float w[4] = {wv.x, wv.y, wv.z, wv.w};
#pragma unroll
    for (int i = 0; i < 4; i++)
#pragma unroll
        for (int j = 0; j < 4; j++) acc[i][j] = fmaf(a[i], w[j], acc[i][j]);
}

// h = relu(x @ W_in + b_in)
__global__ __launch_bounds__(256) void k_in_gemm(const void* __restrict__ A,
                                                 const float* __restrict__ W,
                                                 const float* __restrict__ bias,
                                                 const int* __restrict__ flag,
                                                 float* __restrict__ out, int n) {
    __shared__ float As[64][68];
    __shared__ float Ws[64][64];
    int t = threadIdx.x;
    int v0 = blockIdx.x * 64;
    int tx = t & 15, ty = t >> 4;
    int f16 = *flag;
    float acc[4][4] = {};
    for (int k0 = 0; k0 < 128; k0 += 64) {
#pragma unroll
        for (int j = 0; j < 16; ++j) {
            int i = t + 256 * j;
            int r = i >> 6, k = i & 63;
            int v = v0 + r;
            As[k][r] = (v < n) ? ldf(A, (size_t)v * DIN + k0 + k, f16) : 0.0f;
        }
#pragma unroll
        for (int j = 0; j < 16; ++j) {
            int i = t + 256 * j;
            Ws[i >> 6][i & 63] = W[(size_t)(k0 + (i >> 6)) * 64 + (i & 63)];
        }
        __syncthreads();
#pragma unroll 8
        for (int k = 0; k < 64; ++k) {
            float4 wv = *(const float4*)&Ws[k][tx * 4];
            float4 av = *(const float4*)&As[k][ty * 4];
            mac16(acc, av, wv);
        }
        __syncthreads();
    }
#pragma unroll
    for (int i = 0; i < 4; i++) {
        int v = v0 + ty * 4 + i;
        if (v < n) {
#pragma unroll
            for (int j = 0; j < 4; j++) {
                int f = tx * 4 + j;
                out[(size_t)v * 64 + f] = fmaxf(acc[i][j] + bias[f], 0.0f);
            }
        }
    }
}

// Fused per-layer GEMM:
//   out_gcn  = relu(bn0( g_gcn @ W0 + b0 ))
//   out_sage = relu(bns( g_sage @ Wl + self @ Wr + bs ))
// g is [n][128] interleaved (gcn,sage) float2 pairs; out written same layout.
// self: L0 -> h [n][64] (stride 64, off 0, step 1); L1 -> C1 sage half (128,1,2).
__global__ __launch_bounds__(256) void k_layer_gemm(
        const float* __restrict__ g, const float* __restrict__ self,
        int selfStride, int selfOff, int selfStep,
        const float* __restrict__ W0, const float* __restrict__ Wl,
        const float* __restrict__ Wr,
        const float* __restrict__ b0, const float* __restrict__ bs,
        const float* __restrict__ bn0, const float* __restrict__ bns,
        float* __restrict__ out, int n) {
    __shared__ float Ag[64][68];
    __shared__ float Asg[64][68];
    __shared__ float Wa[64][64];
    __shared__ float Wb[64][64];
    int t = threadIdx.x;
    int v0 = blockIdx.x * 64;
    int tx = t & 15, ty = t >> 4;
    float accg[4][4] = {};
    float accs[4][4] = {};
    // phase 1: stage gather outputs (both halves) + W0/Wl
#pragma unroll
    for (int j = 0; j < 16; ++j) {
        int i = t + 256 * j;
        int r = i >> 6, k = i & 63;
        int v = v0 + r;
        float2 val = make_float2(0.0f, 0.0f);
        if (v < n) val = *(const float2*)&g[(size_t)v * 128 + 2 * k];
        Ag[k][r] = val.x;
        Asg[k][r] = val.y;
        Wa[i >> 6][i & 63] = W0[i];
        Wb[i >> 6][i & 63] = Wl[i];
    }
    __syncthreads();
#pragma unroll 4
    for (int k = 0; k < 64; ++k) {
        float4 w0 = *(const float4*)&Wa[k][tx * 4];
        float4 wl = *(const float4*)&Wb[k][tx * 4];
        float4 ag = *(const float4*)&Ag[k][ty * 4];
        float4 as = *(const float4*)&Asg[k][ty * 4];
        mac16(accg, ag, w0);
        mac16(accs, as, wl);
    }
    __syncthreads();
    // phase 2: stage self + Wr ; accumulate into sage
#pragma unroll
    for (int j = 0; j < 16; ++j) {
        int i = t + 256 * j;
        int r = i >> 6, k = i & 63;
        int v = v0 + r;
        Ag[k][r] = (v < n) ? self[(size_t)v * selfStride + selfOff + k * selfStep] : 0.0f;
        Wa[i >> 6][i & 63] = Wr[i];
    }
    __syncthreads();
#pragma unroll 4
    for (int k = 0; k < 64; ++k) {
        float4 wr = *(const float4*)&Wa[k][tx * 4];
        float4 av = *(const float4*)&Ag[k][ty * 4];
        mac16(accs, av, wr);
    }
    // epilogue: BN + ReLU both branches, interleaved float2 store
#pragma unroll
    for (int i = 0; i < 4; i++) {
        int v = v0 + ty * 4 + i;
        if (v < n) {
#pragma unroll
            for (int j = 0; j < 4; j++) {
                int f = tx * 4 + j;
                float yg = accg[i][j] + b0[f];
                yg = (yg - bn0[128 + f]) * rsqrtf(bn0[192 + f] + EPSV) * bn0[f] + bn0[64 + f];
                float ys = accs[i][j] + bs[f];
                ys = (ys - bns[128 + f]) * rsqrtf(bns[192 + f] + EPSV) * bns[f] + bns[64 + f];
                *(float2*)&out[(size_t)v * 128 + 2 * f] =
                    make_float2(fmaxf(yg, 0.0f), fmaxf(ys, 0.0f));
            }
        }
    }
}

// ---------------- fused dual gathers (1 wave = 1 node, lane = feature) ----------------
// L0: read h rows once; produce GCN-normalized sum and SAGE mean, interleaved.
__global__ __launch_bounds__(256) void k_gather0(const float* __restrict__ h,
                                                 const float* __restrict__ dinv,
                                                 const float* __restrict__ cinv,
                                                 const int* __restrict__ rowptr,
                                                 const int* __restrict__ csr_src,
                                                 float* __restrict__ g, int n) {
    int wid = threadIdx.x >> 6, lane = threadIdx.x & 63;
    int v = blockIdx.x * 4 + wid;
    if (v >= n) return;
    int beg = rowptr[v], end = rowptr[v + 1];
    float accg = 0.0f, accs = 0.0f;
    int i = beg;
    for (; i + 4 <= end; i += 4) {
        int s0 = csr_src[i], s1 = csr_src[i + 1], s2 = csr_src[i + 2], s3 = csr_src[i + 3];
        float x0 = h[(size_t)s0 * 64 + lane], x1 = h[(size_t)s1 * 64 + lane];
        float x2 = h[(size_t)s2 * 64 + lane], x3 = h[(size_t)s3 * 64 + lane];
        float w0 = dinv[s0], w1 = dinv[s1], w2 = dinv[s2], w3 = dinv[s3];
        accg = fmaf(x0, w0, accg); accg = fmaf(x1, w1, accg);
        accg = fmaf(x2, w2, accg); accg = fmaf(x3, w3, accg);
        accs += x0 + x1 + x2 + x3;
    }
    for (; i < end; ++i) {
        int s = csr_src[i];
        float x = h[(size_t)s * 64 + lane];
        accg = fmaf(x, dinv[s], accg);
        accs += x;
    }
    float dv = dinv[v];
    float yg = dv * (accg + dv * h[(size_t)v * 64 + lane]);
    float ys = cinv[v] * accs;
    *(float2*)&g[(size_t)v * 128 + 2 * lane] = make_float2(yg, ys);
}

// L1: read interleaved C rows (512B float2/lane); both branches in one pass.
__global__ __launch_bounds__(256) void k_gather1(const float* __restrict__ C,
                                                 const float* __restrict__ dinv,
                                                 const float* __restrict__ cinv,
                                                 const int* __restrict__ rowptr,
                                                 const int* __restrict__ csr_src,
                                                 float* __restrict__ g, int n) {
    int wid = threadIdx.x >> 6, lane = threadIdx.x & 63;
    int v = blockIdx.x * 4 + wid;
    if (v >= n) return;
    int beg = rowptr[v], end = rowptr[v + 1];
    float accg = 0.0f, accs = 0.0f;
    int i = beg;
    for (; i + 4 <= end; i += 4) {
        int s0 = csr_src[i], s1 = csr_src[i + 1], s2 = csr_src[i + 2], s3 = csr_src[i + 3];
        float2 x0 = *(const float2*)&C[(size_t)s0 * 128 + 2 * lane];
        float2 x1 = *(const float2*)&C[(size_t)s1 * 128 + 2 * lane];
        float2 x2 = *(const float2*)&C[(size_t)s2 * 128 + 2 * lane];
        float2 x3 = *(const float2*)&C[(size_t)s3 * 128 + 2 * lane];
        float w0 = dinv[s0], w1 = dinv[s1], w2 = dinv[s2], w3 = dinv[s3];
        accg = fmaf(x0.x, w0, accg); accg = fmaf(x1.x, w1, accg);
        accg = fmaf(x2.x, w2, accg); accg = fmaf(x3.x, w3, accg);
        accs += x0.y + x1.y + x2.y + x3.y;
    }
    for (; i < end; ++i) {
        int s = csr_src[i];
        float2 x = *(const float2*)&C[(size_t)s * 128 + 2 * lane];
        accg = fmaf(x.x, dinv[s], accg);
        accs += x.y;
    }
    float dv = dinv[v];
    float2 self = *(const float2*)&C[(size_t)v * 128 + 2 * lane];
    float yg = dv * (accg + dv * self.x);
    float ys = cinv[v] * accs;
    *(float2*)&g[(size_t)v * 128 + 2 * lane] = make_float2(yg, ys);
}

// ---------------- pooling over interleaved final feats (both halves at once) -----------
__global__ __launch_bounds__(256) void k_pool2(const float* __restrict__ X2,
                                               const int* __restrict__ batch,
                                               float* __restrict__ pooled, int n) {
    int wid = threadIdx.x >> 6, lane = threadIdx.x & 63;
    int v0 = blockIdx.x * 64 + wid * 16;
    float ag = 0.0f, as = 0.0f;
    int g = -1;
    for (int j = 0; j < 16; ++j) {
        int v = v0 + j;
        if (v >= n) break;
        int b = batch[v];
        if (b != g) {
            if (g >= 0) {
                atomicAdd(&pooled[g * 128 + lane], ag);
                atomicAdd(&pooled[g * 128 + 64 + lane], as);
            }
            g = b; ag = 0.0f; as = 0.0f;
        }
        float2 val = *(const float2*)&X2[(size_t)v * 128 + 2 * lane];
        ag += val.x; as += val.y;
    }
    if (g >= 0) {
        atomicAdd(&pooled[g * 128 + lane], ag);
        atomicAdd(&pooled[g * 128 + 64 + lane], as);
    }
}

// ---------------- head MLP (single block) ----------------
__global__ __launch_bounds__(256) void k_head(const float* __restrict__ pooled,
                                              const int* __restrict__ gcnt,
                                              const float* __restrict__ P_,
                                              const int* __restrict__ flag,
                                              void* __restrict__ out) {
    const float* f1W = P_ + PW_F1W;
    const float* f1b = P_ + PW_F1B;
    const float* bn1 = P_ + PW_BN1;
    const float* f2W = P_ + PW_F2W;
    const float* f2b = P_ + PW_F2B;
    const float* bn2 = P_ + PW_BN2;
    const float* f3W = P_ + PW_F3W;
    const float* f3b = P_ + PW_F3B;
    __shared__ float P[64][128];
    __shared__ float Z1[64][64];
    __shared__ float Z2[64][32];
    int t = threadIdx.x;
    for (int i = t; i < 64 * 128; i += 256) {
        int g = i >> 7;
        float c = fmaxf((float)gcnt[g], 1.0f);
        P[g][i & 127] = pooled[i] / c;
    }
    __syncthreads();
    for (int o = t; o < 64 * 64; o += 256) {
        int g = o >> 6, f = o & 63;
        float acc = 0.0f;
        for (int c = 0; c < 128; ++c) acc = fmaf(P[g][c], f1W[c * 64 + f], acc);
        float y = acc + f1b[f];
        y = (y - bn1[128 + f]) * rsqrtf(bn1[192 + f] + EPSV) * bn1[f] + bn1[64 + f];
        Z1[g][f] = fmaxf(y, 0.0f);
    }
    __syncthreads();
    for (int o = t; o < 64 * 32; o += 256) {
        int g = o >> 5, f = o & 31;
        float acc = 0.0f;
        for (int c = 0; c < 64; ++c) acc = fmaf(Z1[g][c], f2W[c * 32 + f], acc);
        float y = acc + f2b[f];
        y = (y - bn2[64 + f]) * rsqrtf(bn2[96 + f] + EPSV) * bn2[f] + bn2[32 + f];
        Z2[g][f] = fmaxf(y, 0.0f);
    }
    __syncthreads();
    if (t < 64) {
        float acc = 0.0f;
        for (int c = 0; c < 32; ++c) acc = fmaf(Z2[t][c], f3W[c], acc);
        float y = acc + f3b[0];
        if (*flag) ((__hip_bfloat16*)out)[t] = __float2bfloat16(y);
        else       ((float*)out)[t] = y;
    }
}

extern "C" void kernel_launch(void* const* d_in, const int* in_sizes, int n_in,
                              void* d_out, int out_size, void* d_ws, size_t ws_size,
                              hipStream_t stream) {
    (void)in_sizes; (void)n_in; (void)out_size; (void)ws_size;
    const void* x     = d_in[0];
    const int*  eidx  = (const int*)d_in[1];
    const int*  batch = (const int*)d_in[2];

    const int n = NN, E = NE;
    const int* src = eidx;
    const int* dst = eidx + E;

    char* w = (char*)d_ws;
    float* h   = (float*)w;  w += (size_t)n * 64 * 4;    // [n][64]
    float* g   = (float*)w;  w += (size_t)n * 128 * 4;   // gather out, interleaved
    float* C1  = (float*)w;  w += (size_t)n * 128 * 4;   // layer-0 out, interleaved
    float* C2  = (float*)w;  w += (size_t)n * 128 * 4;   // layer-1 out, interleaved
    int*   indeg  = (int*)w;  w += (size_t)n * 4;
    int*   rowptr = (int*)w;  w += (size_t)(n + 8) * 4;
    int*   rank   = (int*)w;  w += (size_t)E * 4;
    int*   csr_src = (int*)w; w += (size_t)E * 4;
    float* dinv  = (float*)w; w += (size_t)n * 4;
    float* cinv  = (float*)w; w += (size_t)n * 4;
    int*   gcnt  = (int*)w;  w += 64 * 4;
    float* pooled = (float*)w; w += 64 * 128 * 4;
    int*   cnt   = (int*)w;  w += 8;
    int*   flag  = (int*)w;  w += 8;
    float* prm   = (float*)w;                  // PW_TOT floats

    hipMemsetAsync(indeg, 0, (size_t)n * 4, stream);
    hipMemsetAsync(gcnt, 0, 64 * 4 + 64 * 128 * 4, stream);  // gcnt + pooled contiguous
    hipMemsetAsync(cnt, 0, 4, stream);

    dim3 b256(256);

    // dtype detection + param conversion
    const int DETN = 262144;
    k_detect<<<dim3(DETN / 256), b256, 0, stream>>>((const unsigned short*)x, cnt, DETN);
    k_resolve<<<1, 64, 0, stream>>>(cnt, flag);
    PSrc ps;
    for (int i = 0; i < 17; ++i) ps.p[i] = d_in[3 + i];
    k_cvt<<<dim3((PW_TOT + 255) / 256), b256, 0, stream>>>(ps, flag, prm);

    // CSR build (rank trick: no atomics in fill)
    k_degree<<<dim3((E + 255) / 256), b256, 0, stream>>>(dst, indeg, rank, E);
    k_scan<<<1, 1024, 0, stream>>>(indeg, rowptr, dinv, cinv, n);
    k_fill<<<dim3((E + 255) / 256), b256, 0, stream>>>(src, dst, rowptr, rank, csr_src, E);
    k_gcount<<<dim3((n + 1023) / 1024), b256, 0, stream>>>(batch, gcnt, n);

    int gGemm = (n + 63) / 64;
    int gGath = (n + 3) / 4;
    int gPool = (n + 63) / 64;

    k_in_gemm<<<gGemm, b256, 0, stream>>>(x, prm + PW_WIN, prm + PW_BIN, flag, h, n);

    // layer 0: dual gather of h -> g ; fused GEMMs -> C1 (self term from h)
    k_gather0<<<gGath, b256, 0, stream>>>(h, dinv, cinv, rowptr, csr_src, g, n);
    k_layer_gemm<<<gGemm, b256, 0, stream>>>(g, h, 64, 0, 1,
        prm + PW_GCNW, prm + PW_SWL, prm + PW_SWR,
        prm + PW_GCNB, prm + PW_SB, prm + PW_GCNBN, prm + PW_SBN, C1, n);

    // layer 1: dual gather of C1 -> g ; fused GEMMs -> C2 (self = C1 sage half)
    k_gather1<<<gGath, b256, 0, stream>>>(C1, dinv, cinv, rowptr, csr_src, g, n);
    k_layer_gemm<<<gGemm, b256, 0, stream>>>(g, C1, 128, 1, 2,
        prm + PW_GCNW + 4096, prm + PW_SWL + 4096, prm + PW_SWR + 4096,
        prm + PW_GCNB + 64, prm + PW_SB + 64, prm + PW_GCNBN + 256, prm + PW_SBN + 256, C2, n);

    // pooling (both halves) + head
    k_pool2<<<gPool, b256, 0, stream>>>(C2, batch, pooled, n);
    k_head<<<1, b256, 0, stream>>>(pooled, gcnt, prm, flag, d_out);
}